// Round 8
// baseline (241.401 us; speedup 1.0000x reference)
//
#include <hip/hip_runtime.h>
#include <math.h>

#define BB 1024
#define NN 1024
#define DD 64
#define MARGIN_V 0.5f
#define EPS_V 1e-6f
#define QSPLIT 4               // blocks per batch row in k_dist
#define QCOLS (NN / QSPLIT)    // 256 columns per block

typedef float f32x4 __attribute__((ext_vector_type(4)));

// ---------------------------------------------------------------------------
// Kernel 1: 4096 blocks = 4 per batch row. Coalesced group-of-16 layout
// (lane gl reads the f32x4 of column n at elem gl*4 -> 1KB/wave-instr).
// THE FIX vs R7: each phase's 12 loads (4 cols x {a,p,g}) live in ONE asm
// block, terminated by s_waitcnt vmcnt(0) inside the same statement. A single
// asm statement cannot be split, interleaved, or conservatively drained by
// the backend -> 12KB per wave genuinely in flight (R4/R6/R7 all showed the
// compiler caps in-flight loads at ~1-6, pinning read BW at 3.94 TB/s even
// when data is L3-resident).
// ---------------------------------------------------------------------------
__global__ __launch_bounds__(256) void k_dist(const float* __restrict__ a,
                                              const float* __restrict__ p,
                                              const float* __restrict__ g,
                                              float* __restrict__ ws_loss,
                                              float* __restrict__ ws_score,
                                              int* __restrict__ ws_idx,
                                              int* __restrict__ ws_valid)
{
    const int blk  = blockIdx.x;       // 0..4095
    const int b    = blk >> 2;
    const int q    = blk & 3;
    const int tid  = threadIdx.x;
    const int lane = tid & 63;
    const int wave = tid >> 6;         // 0..3
    const int grp  = lane >> 4;        // 0..3
    const int gl   = lane & 15;        // lane within 16-lane group
    const int group = wave * 4 + grp;  // 0..15

    const int ncol0 = q * QCOLS + group;   // group's cols: ncol0 + i*16, i=0..15
    // per-lane byte offset of (b, ncol0, gl*4); max ~268MB < 2^31, fits u32
    const unsigned int boff0 =
        ((unsigned int)b * (NN * DD) + (unsigned int)ncol0 * DD + (unsigned int)gl * 4) * 4u;

    float loss_acc   = 0.f;
    float best_score = -INFINITY;
    int   best_idx   = 0x7fffffff;

    #pragma unroll 1
    for (int ph = 0; ph < 4; ++ph) {
        // ---- forced 12-load burst: ONE asm statement, wait included ----
        const unsigned int o0 = boff0 + (unsigned int)(ph * 4 + 0) * (16u * DD * 4u);
        const unsigned int o1 = boff0 + (unsigned int)(ph * 4 + 1) * (16u * DD * 4u);
        const unsigned int o2 = boff0 + (unsigned int)(ph * 4 + 2) * (16u * DD * 4u);
        const unsigned int o3 = boff0 + (unsigned int)(ph * 4 + 3) * (16u * DD * 4u);

        f32x4 va0, va1, va2, va3, vp0, vp1, vp2, vp3, vg0, vg1, vg2, vg3;
        asm volatile(
            "global_load_dwordx4 %0, %12, %16\n\t"
            "global_load_dwordx4 %4, %12, %17\n\t"
            "global_load_dwordx4 %8, %12, %18\n\t"
            "global_load_dwordx4 %1, %13, %16\n\t"
            "global_load_dwordx4 %5, %13, %17\n\t"
            "global_load_dwordx4 %9, %13, %18\n\t"
            "global_load_dwordx4 %2, %14, %16\n\t"
            "global_load_dwordx4 %6, %14, %17\n\t"
            "global_load_dwordx4 %10, %14, %18\n\t"
            "global_load_dwordx4 %3, %15, %16\n\t"
            "global_load_dwordx4 %7, %15, %17\n\t"
            "global_load_dwordx4 %11, %15, %18\n\t"
            "s_waitcnt vmcnt(0)"
            : "=&v"(va0), "=&v"(va1), "=&v"(va2), "=&v"(va3),
              "=&v"(vp0), "=&v"(vp1), "=&v"(vp2), "=&v"(vp3),
              "=&v"(vg0), "=&v"(vg1), "=&v"(vg2), "=&v"(vg3)
            : "v"(o0), "v"(o1), "v"(o2), "v"(o3),
              "s"(a), "s"(p), "s"(g)
            : "memory");
        __builtin_amdgcn_sched_barrier(0);

        // ---- pure-VALU accumulate (4 cols, independent chains) ----
        float accp[4], accn[4];
        {
            const f32x4 va[4] = {va0, va1, va2, va3};
            const f32x4 vp[4] = {vp0, vp1, vp2, vp3};
            const f32x4 vg[4] = {vg0, vg1, vg2, vg3};
            #pragma unroll
            for (int i = 0; i < 4; ++i) {
                float sp = 0.f, sn = 0.f, t;
                #pragma unroll
                for (int e = 0; e < 4; ++e) {
                    t = va[i][e] - vp[i][e] + EPS_V; sp += t * t;
                    t = va[i][e] - vg[i][e] + EPS_V; sn += t * t;
                }
                accp[i] = sp; accn[i] = sn;
            }
        }

        // ---- batched 16-lane-group reduces (8 independent 4-deep chains) ----
        #pragma unroll
        for (int i = 0; i < 4; ++i) {
            #pragma unroll
            for (int m = 1; m < 16; m <<= 1) {
                accp[i] += __shfl_xor(accp[i], m, 64);
                accn[i] += __shfl_xor(accn[i], m, 64);
            }
        }

        // ---- tail: lane gl == ph*4+i owns column ncol0 + (ph*4+i)*16 ----
        #pragma unroll
        for (int i = 0; i < 4; ++i) {
            if (gl == ph * 4 + i) {
                const int n = ncol0 + (ph * 4 + i) * 16;
                const float diff = MARGIN_V + sqrtf(accp[i]) - sqrtf(accn[i]);
                loss_acc += fmaxf(diff, 0.f);
                const float sc = (diff > 0.f) ? sqrtf(accn[i]) : -INFINITY;
                if (sc > best_score || (sc == best_score && n < best_idx)) {
                    best_score = sc; best_idx = n;
                }
            }
        }
    }

    // ---- wave reduce: sum(loss), argmax(score) with first-index tie-break ----
    for (int m = 1; m < 64; m <<= 1) {
        loss_acc += __shfl_xor(loss_acc, m, 64);
        const float so = __shfl_xor(best_score, m, 64);
        const int   io = __shfl_xor(best_idx, m, 64);
        if (so > best_score || (so == best_score && io < best_idx)) {
            best_score = so; best_idx = io;
        }
    }

    __shared__ float s_loss[4];
    __shared__ float s_score[4];
    __shared__ int   s_idx[4];
    if ((tid & 63) == 0) {
        s_loss[wave]  = loss_acc;
        s_score[wave] = best_score;
        s_idx[wave]   = best_idx;
    }
    __syncthreads();
    if (tid == 0) {
        float ls = 0.f, bs = -INFINITY;
        int   bi = 0x7fffffff;
        for (int k = 0; k < 4; ++k) {
            ls += s_loss[k];
            const float sc = s_score[k]; const int ix = s_idx[k];
            if (sc > bs || (sc == bs && ix < bi)) { bs = sc; bi = ix; }
        }
        ws_loss[blk]  = ls;
        ws_score[blk] = bs;
        ws_idx[blk]   = bi;
        ws_valid[blk] = (bs > -INFINITY) ? 1 : 0;
    }
}

// ---------------------------------------------------------------------------
// Kernel 2 (single block, 1024 threads): thread b merges its QSPLIT partials
// (first-index tie-break), writes sel/has_valid, block-reduces loss -> mean.
// ---------------------------------------------------------------------------
__global__ __launch_bounds__(1024) void k_merge(const float* __restrict__ ws_loss,
                                                const float* __restrict__ ws_score,
                                                const int* __restrict__ ws_idx,
                                                const int* __restrict__ ws_valid,
                                                float* __restrict__ out_loss,
                                                int* __restrict__ ws_sel,
                                                float* __restrict__ out_hasvalid)
{
    const int b = threadIdx.x;
    float ls = 0.f;
    float bs = -INFINITY;
    int   bi = 0x7fffffff;
    int   av = 0;
    for (int qq = 0; qq < QSPLIT; ++qq) {
        const int idx = b * QSPLIT + qq;
        const float sc = ws_score[idx];
        const int   ix = ws_idx[idx];
        if (sc > bs || (sc == bs && ix < bi)) { bs = sc; bi = ix; }
        ls += ws_loss[idx];
        av |= ws_valid[idx];
    }
    ws_sel[b] = bi;
    out_hasvalid[b] = av ? 1.0f : 0.0f;

    __shared__ float s[16];
    float v = ls;
    for (int m = 1; m < 64; m <<= 1) v += __shfl_xor(v, m, 64);
    if ((b & 63) == 0) s[b >> 6] = v;
    __syncthreads();
    if (b == 0) {
        float tot = 0.f;
        for (int k = 0; k < 16; ++k) tot += s[k];
        out_loss[0] = tot / (float)((size_t)BB * NN);
    }
}

// ---------------------------------------------------------------------------
// Kernel 3: hard_neg[b] = negative[sel_col[b]].  Scalar coalesced copies
// (dst is 4B-misaligned vs 16B). Non-temporal stores: output never re-read
// (cut gather from ~65 to ~25-40 us in R4/R6).
// ---------------------------------------------------------------------------
__global__ __launch_bounds__(256) void k_gather(const float* __restrict__ g,
                                                const int* __restrict__ ws_sel,
                                                float* __restrict__ out_hn)
{
    const int b   = blockIdx.y;
    const int sel = ws_sel[b];
    const float* __restrict__ src = g      + (size_t)sel * (NN * DD);
    float* __restrict__       dst = out_hn + (size_t)b   * (NN * DD);
    const int t = blockIdx.x * blockDim.x + threadIdx.x;   // 0..8191
    #pragma unroll
    for (int k = 0; k < (NN * DD) / 8192; ++k) {
        const int idx = t + k * 8192;
        __builtin_nontemporal_store(src[idx], dst + idx);
    }
}

extern "C" void kernel_launch(void* const* d_in, const int* in_sizes, int n_in,
                              void* d_out, int out_size, void* d_ws, size_t ws_size,
                              hipStream_t stream) {
    const float* anchor   = (const float*)d_in[0];
    const float* positive = (const float*)d_in[1];
    const float* negative = (const float*)d_in[2];
    float* out = (float*)d_out;

    // out layout: [0] loss | [1 .. 1+B*N*D) hard_neg | [1+B*N*D .. +B) has_valid
    float* out_loss     = out;
    float* out_hard_neg = out + 1;
    float* out_hasvalid = out + 1 + (size_t)BB * NN * DD;

    // ws layout: 4096 loss | 4096 score | 4096 idx | 4096 valid | 1024 sel
    float* ws_loss  = (float*)d_ws;
    float* ws_score = ws_loss + BB * QSPLIT;
    int*   ws_idx   = (int*)(ws_score + BB * QSPLIT);
    int*   ws_valid = ws_idx + BB * QSPLIT;
    int*   ws_sel   = ws_valid + BB * QSPLIT;

    k_dist<<<dim3(BB * QSPLIT), dim3(256), 0, stream>>>(anchor, positive, negative,
                                                        ws_loss, ws_score, ws_idx, ws_valid);
    k_merge<<<dim3(1), dim3(1024), 0, stream>>>(ws_loss, ws_score, ws_idx, ws_valid,
                                                out_loss, ws_sel, out_hasvalid);
    k_gather<<<dim3(32, BB), dim3(256), 0, stream>>>(negative, ws_sel, out_hard_neg);
}

// Round 9
// 238.064 us; speedup vs baseline: 1.0140x; 1.0140x over previous
//
#include <hip/hip_runtime.h>
#include <math.h>

#define BB 1024
#define NN 1024
#define DD 64
#define MARGIN_V 0.5f
#define EPS_V 1e-6f
#define QSPLIT 4               // blocks per batch row in k_dist
#define QCOLS (NN / QSPLIT)    // 256 columns per block

typedef float f32x4 __attribute__((ext_vector_type(4)));

// Issue 12 coalesced global_load_dwordx4 (4 cols x {a,p,g}) in ONE asm block.
// No waitcnt inside: the wait is counted, issued separately (T4 pattern).
#define ISSUE12(A0,A1,A2,A3,P0,P1,P2,P3,G0,G1,G2,G3, PH)                      \
    do {                                                                       \
        const unsigned int _o0 = boff0 + (unsigned int)((PH)*4 + 0) * 4096u;   \
        const unsigned int _o1 = boff0 + (unsigned int)((PH)*4 + 1) * 4096u;   \
        const unsigned int _o2 = boff0 + (unsigned int)((PH)*4 + 2) * 4096u;   \
        const unsigned int _o3 = boff0 + (unsigned int)((PH)*4 + 3) * 4096u;   \
        asm volatile(                                                          \
            "global_load_dwordx4 %0, %12, %16\n\t"                             \
            "global_load_dwordx4 %4, %12, %17\n\t"                             \
            "global_load_dwordx4 %8, %12, %18\n\t"                             \
            "global_load_dwordx4 %1, %13, %16\n\t"                             \
            "global_load_dwordx4 %5, %13, %17\n\t"                             \
            "global_load_dwordx4 %9, %13, %18\n\t"                             \
            "global_load_dwordx4 %2, %14, %16\n\t"                             \
            "global_load_dwordx4 %6, %14, %17\n\t"                             \
            "global_load_dwordx4 %10, %14, %18\n\t"                            \
            "global_load_dwordx4 %3, %15, %16\n\t"                             \
            "global_load_dwordx4 %7, %15, %17\n\t"                             \
            "global_load_dwordx4 %11, %15, %18\n\t"                            \
            : "=&v"(A0), "=&v"(A1), "=&v"(A2), "=&v"(A3),                      \
              "=&v"(P0), "=&v"(P1), "=&v"(P2), "=&v"(P3),                      \
              "=&v"(G0), "=&v"(G1), "=&v"(G2), "=&v"(G3)                       \
            : "v"(_o0), "v"(_o1), "v"(_o2), "v"(_o3),                          \
              "s"(a), "s"(p), "s"(g)                                           \
            : "memory");                                                       \
    } while (0)

// Consume one bank: accumulate, 16-lane-group shfl reduce, tail update.
#define CONSUME12(A0,A1,A2,A3,P0,P1,P2,P3,G0,G1,G2,G3, PH)                    \
    do {                                                                       \
        const f32x4 _va[4] = {A0, A1, A2, A3};                                 \
        const f32x4 _vp[4] = {P0, P1, P2, P3};                                 \
        const f32x4 _vg[4] = {G0, G1, G2, G3};                                 \
        float _accp[4], _accn[4];                                              \
        _Pragma("unroll")                                                      \
        for (int _i = 0; _i < 4; ++_i) {                                       \
            float _sp = 0.f, _sn = 0.f, _t;                                    \
            _Pragma("unroll")                                                  \
            for (int _e = 0; _e < 4; ++_e) {                                   \
                _t = _va[_i][_e] - _vp[_i][_e] + EPS_V; _sp += _t * _t;        \
                _t = _va[_i][_e] - _vg[_i][_e] + EPS_V; _sn += _t * _t;        \
            }                                                                  \
            _accp[_i] = _sp; _accn[_i] = _sn;                                  \
        }                                                                      \
        _Pragma("unroll")                                                      \
        for (int _i = 0; _i < 4; ++_i) {                                       \
            _Pragma("unroll")                                                  \
            for (int _m = 1; _m < 16; _m <<= 1) {                              \
                _accp[_i] += __shfl_xor(_accp[_i], _m, 64);                    \
                _accn[_i] += __shfl_xor(_accn[_i], _m, 64);                    \
            }                                                                  \
        }                                                                      \
        _Pragma("unroll")                                                      \
        for (int _i = 0; _i < 4; ++_i) {                                       \
            if (gl == (PH) * 4 + _i) {                                         \
                const int _n = ncol0 + ((PH) * 4 + _i) * 16;                   \
                const float _diff = MARGIN_V + sqrtf(_accp[_i]) - sqrtf(_accn[_i]); \
                loss_acc += fmaxf(_diff, 0.f);                                 \
                const float _sc = (_diff > 0.f) ? sqrtf(_accn[_i]) : -INFINITY;\
                if (_sc > best_score || (_sc == best_score && _n < best_idx)) {\
                    best_score = _sc; best_idx = _n;                           \
                }                                                              \
            }                                                                  \
        }                                                                      \
    } while (0)

// ---------------------------------------------------------------------------
// Kernel 1: 4096 blocks = 4 per batch row. Coalesced group-of-16 layout
// (lane gl reads the f32x4 of column n at elem gl*4 -> 1KB/wave-instr).
// T4 STRUCTURE (new vs R8): 2-deep register double-buffer with COUNTED
// waits. Issue bank(k+1)'s 12 loads, then s_waitcnt vmcnt(12) -- waits only
// for bank(k) -- so 12-24KB stay in flight per wave ACROSS the compute+shfl
// window. R1-R8 all drained vmcnt to 0 each phase (in-flight duty cycle
// ~40%), the anti-pattern the guide's m218 measured at -38..-73%.
// ---------------------------------------------------------------------------
__global__ __launch_bounds__(256) void k_dist(const float* __restrict__ a,
                                              const float* __restrict__ p,
                                              const float* __restrict__ g,
                                              float* __restrict__ ws_loss,
                                              float* __restrict__ ws_score,
                                              int* __restrict__ ws_idx,
                                              int* __restrict__ ws_valid)
{
    const int blk  = blockIdx.x;       // 0..4095
    const int b    = blk >> 2;
    const int q    = blk & 3;
    const int tid  = threadIdx.x;
    const int lane = tid & 63;
    const int wave = tid >> 6;         // 0..3
    const int grp  = lane >> 4;        // 0..3
    const int gl   = lane & 15;        // lane within 16-lane group
    const int group = wave * 4 + grp;  // 0..15

    const int ncol0 = q * QCOLS + group;   // group's cols: ncol0 + i*16, i=0..15
    // per-lane byte offset of (b, ncol0, gl*4); max ~268MB < 2^31, fits u32
    const unsigned int boff0 =
        ((unsigned int)b * (NN * DD) + (unsigned int)ncol0 * DD + (unsigned int)gl * 4) * 4u;

    float loss_acc   = 0.f;
    float best_score = -INFINITY;
    int   best_idx   = 0x7fffffff;

    // two named register banks (static indexing per rule #20)
    f32x4 xa0, xa1, xa2, xa3, xp0, xp1, xp2, xp3, xg0, xg1, xg2, xg3;  // bank A
    f32x4 ya0, ya1, ya2, ya3, yp0, yp1, yp2, yp3, yg0, yg1, yg2, yg3;  // bank B

    // prologue: phase 0 into bank A
    ISSUE12(xa0,xa1,xa2,xa3, xp0,xp1,xp2,xp3, xg0,xg1,xg2,xg3, 0);

    // phase 0: issue ph1 into B, wait for A (12 newest outstanding allowed)
    ISSUE12(ya0,ya1,ya2,ya3, yp0,yp1,yp2,yp3, yg0,yg1,yg2,yg3, 1);
    asm volatile("s_waitcnt vmcnt(12)" ::: "memory");
    __builtin_amdgcn_sched_barrier(0);
    CONSUME12(xa0,xa1,xa2,xa3, xp0,xp1,xp2,xp3, xg0,xg1,xg2,xg3, 0);

    // phase 1: issue ph2 into A, wait for B
    ISSUE12(xa0,xa1,xa2,xa3, xp0,xp1,xp2,xp3, xg0,xg1,xg2,xg3, 2);
    asm volatile("s_waitcnt vmcnt(12)" ::: "memory");
    __builtin_amdgcn_sched_barrier(0);
    CONSUME12(ya0,ya1,ya2,ya3, yp0,yp1,yp2,yp3, yg0,yg1,yg2,yg3, 1);

    // phase 2: issue ph3 into B, wait for A
    ISSUE12(ya0,ya1,ya2,ya3, yp0,yp1,yp2,yp3, yg0,yg1,yg2,yg3, 3);
    asm volatile("s_waitcnt vmcnt(12)" ::: "memory");
    __builtin_amdgcn_sched_barrier(0);
    CONSUME12(xa0,xa1,xa2,xa3, xp0,xp1,xp2,xp3, xg0,xg1,xg2,xg3, 2);

    // phase 3: drain
    asm volatile("s_waitcnt vmcnt(0)" ::: "memory");
    __builtin_amdgcn_sched_barrier(0);
    CONSUME12(ya0,ya1,ya2,ya3, yp0,yp1,yp2,yp3, yg0,yg1,yg2,yg3, 3);

    // ---- wave reduce: sum(loss), argmax(score) with first-index tie-break ----
    for (int m = 1; m < 64; m <<= 1) {
        loss_acc += __shfl_xor(loss_acc, m, 64);
        const float so = __shfl_xor(best_score, m, 64);
        const int   io = __shfl_xor(best_idx, m, 64);
        if (so > best_score || (so == best_score && io < best_idx)) {
            best_score = so; best_idx = io;
        }
    }

    __shared__ float s_loss[4];
    __shared__ float s_score[4];
    __shared__ int   s_idx[4];
    if ((tid & 63) == 0) {
        s_loss[wave]  = loss_acc;
        s_score[wave] = best_score;
        s_idx[wave]   = best_idx;
    }
    __syncthreads();
    if (tid == 0) {
        float ls = 0.f, bs = -INFINITY;
        int   bi = 0x7fffffff;
        for (int k = 0; k < 4; ++k) {
            ls += s_loss[k];
            const float sc = s_score[k]; const int ix = s_idx[k];
            if (sc > bs || (sc == bs && ix < bi)) { bs = sc; bi = ix; }
        }
        ws_loss[blk]  = ls;
        ws_score[blk] = bs;
        ws_idx[blk]   = bi;
        ws_valid[blk] = (bs > -INFINITY) ? 1 : 0;
    }
}

// ---------------------------------------------------------------------------
// Kernel 2 (single block, 1024 threads): thread b merges its QSPLIT partials
// (first-index tie-break), writes sel/has_valid, block-reduces loss -> mean.
// ---------------------------------------------------------------------------
__global__ __launch_bounds__(1024) void k_merge(const float* __restrict__ ws_loss,
                                                const float* __restrict__ ws_score,
                                                const int* __restrict__ ws_idx,
                                                const int* __restrict__ ws_valid,
                                                float* __restrict__ out_loss,
                                                int* __restrict__ ws_sel,
                                                float* __restrict__ out_hasvalid)
{
    const int b = threadIdx.x;
    float ls = 0.f;
    float bs = -INFINITY;
    int   bi = 0x7fffffff;
    int   av = 0;
    for (int qq = 0; qq < QSPLIT; ++qq) {
        const int idx = b * QSPLIT + qq;
        const float sc = ws_score[idx];
        const int   ix = ws_idx[idx];
        if (sc > bs || (sc == bs && ix < bi)) { bs = sc; bi = ix; }
        ls += ws_loss[idx];
        av |= ws_valid[idx];
    }
    ws_sel[b] = bi;
    out_hasvalid[b] = av ? 1.0f : 0.0f;

    __shared__ float s[16];
    float v = ls;
    for (int m = 1; m < 64; m <<= 1) v += __shfl_xor(v, m, 64);
    if ((b & 63) == 0) s[b >> 6] = v;
    __syncthreads();
    if (b == 0) {
        float tot = 0.f;
        for (int k = 0; k < 16; ++k) tot += s[k];
        out_loss[0] = tot / (float)((size_t)BB * NN);
    }
}

// ---------------------------------------------------------------------------
// Kernel 3: hard_neg[b] = negative[sel_col[b]].  Scalar coalesced copies
// (dst is 4B-misaligned vs 16B). Non-temporal stores: output never re-read.
// ---------------------------------------------------------------------------
__global__ __launch_bounds__(256) void k_gather(const float* __restrict__ g,
                                                const int* __restrict__ ws_sel,
                                                float* __restrict__ out_hn)
{
    const int b   = blockIdx.y;
    const int sel = ws_sel[b];
    const float* __restrict__ src = g      + (size_t)sel * (NN * DD);
    float* __restrict__       dst = out_hn + (size_t)b   * (NN * DD);
    const int t = blockIdx.x * blockDim.x + threadIdx.x;   // 0..8191
    #pragma unroll
    for (int k = 0; k < (NN * DD) / 8192; ++k) {
        const int idx = t + k * 8192;
        __builtin_nontemporal_store(src[idx], dst + idx);
    }
}

extern "C" void kernel_launch(void* const* d_in, const int* in_sizes, int n_in,
                              void* d_out, int out_size, void* d_ws, size_t ws_size,
                              hipStream_t stream) {
    const float* anchor   = (const float*)d_in[0];
    const float* positive = (const float*)d_in[1];
    const float* negative = (const float*)d_in[2];
    float* out = (float*)d_out;

    // out layout: [0] loss | [1 .. 1+B*N*D) hard_neg | [1+B*N*D .. +B) has_valid
    float* out_loss     = out;
    float* out_hard_neg = out + 1;
    float* out_hasvalid = out + 1 + (size_t)BB * NN * DD;

    // ws layout: 4096 loss | 4096 score | 4096 idx | 4096 valid | 1024 sel
    float* ws_loss  = (float*)d_ws;
    float* ws_score = ws_loss + BB * QSPLIT;
    int*   ws_idx   = (int*)(ws_score + BB * QSPLIT);
    int*   ws_valid = ws_idx + BB * QSPLIT;
    int*   ws_sel   = ws_valid + BB * QSPLIT;

    k_dist<<<dim3(BB * QSPLIT), dim3(256), 0, stream>>>(anchor, positive, negative,
                                                        ws_loss, ws_score, ws_idx, ws_valid);
    k_merge<<<dim3(1), dim3(1024), 0, stream>>>(ws_loss, ws_score, ws_idx, ws_valid,
                                                out_loss, ws_sel, out_hasvalid);
    k_gather<<<dim3(32, BB), dim3(256), 0, stream>>>(negative, ws_sel, out_hard_neg);
}